// Round 7
// baseline (273.697 us; speedup 1.0000x reference)
//
#include <hip/hip_runtime.h>
#include <math.h>

#define B_ROWS 8192
#define C_COLS 4096
#define D_DIM  1024
#define EPSN   1e-12f

typedef float v4f __attribute__((ext_vector_type(4)));
typedef short v8s __attribute__((ext_vector_type(8)));

__device__ __forceinline__ unsigned short bf16_rtn(float x) {
    unsigned int u = __float_as_uint(x);
    u += 0x7fffu + ((u >> 16) & 1u);
    return (unsigned short)(u >> 16);
}

// strict total order (value desc, index asc) == first-occurrence argmax
__device__ __forceinline__ bool better_vi(float v, int i, float V, int I) {
    return (v > V) || (v == V && i < I);
}

// ---------------------------------------------------------------------------
// Kernel 1: wave-per-row normalize + bf16 convert. (R3-proven, unchanged)
// ---------------------------------------------------------------------------
__global__ __launch_bounds__(256) void prep_kernel(
    const float* __restrict__ emb, const float* __restrict__ cen,
    unsigned short* __restrict__ Ah, unsigned short* __restrict__ Bh,
    float* __restrict__ inv_a, float* __restrict__ inv_b)
{
    const int lane = threadIdx.x & 63;
    const int wid  = blockIdx.x * 4 + (threadIdx.x >> 6);
    const float* src; unsigned short* dst; float* invp; int r;
    if (wid < B_ROWS) { src = emb; r = wid;          dst = Ah; invp = inv_a; }
    else              { src = cen; r = wid - B_ROWS; dst = Bh; invp = inv_b; }

    const float* rp = src + (size_t)r * D_DIM;
    float4 v[4];
    float ss = 0.0f;
    #pragma unroll
    for (int j = 0; j < 4; ++j) {
        v[j] = *(const float4*)(rp + (j * 64 + lane) * 4);
        ss += v[j].x * v[j].x + v[j].y * v[j].y + v[j].z * v[j].z + v[j].w * v[j].w;
    }
    #pragma unroll
    for (int off = 1; off < 64; off <<= 1) ss += __shfl_xor(ss, off, 64);

    const float iv = 1.0f / fmaxf(sqrtf(ss), EPSN);
    if (lane == 0) invp[r] = iv;

    unsigned short* dp = dst + (size_t)r * D_DIM;
    #pragma unroll
    for (int j = 0; j < 4; ++j) {
        ushort4 H;
        H.x = bf16_rtn(v[j].x * iv);
        H.y = bf16_rtn(v[j].y * iv);
        H.z = bf16_rtn(v[j].z * iv);
        H.w = bf16_rtn(v[j].w * iv);
        *(ushort4*)(dp + (j * 64 + lane) * 4) = H;
    }
}

// ---------------------------------------------------------------------------
// Kernel 2 (R12): flatmm-style hybrid. Evidence R6-R11: schedule variants
// don't move perf; LDS port (~43 us/CU of read+write) is the largest pipe.
// So: B operand SKIPS LDS entirely -- per-lane global_load_dwordx4 in exact
// fragment layout (L2-served, 2x re-read accepted); A-only LDS (16 KB,
// proven granule swizzle). B loads issue BEFORE __syncthreads so their
// latency hides under the staging drain already being paid. Keeps the
// R6/R10-proven simple loop: stage+loadB -> sync -> ds_read A + 32 MFMA ->
// sync. 128x128 tile, 256 thr (2Mx2N waves), acc[4][4]. LDS reads halve
// (2.15 -> 1.07 GB), writes 805 -> 537 MB. launch_bounds(256,3) is a floor:
// if regs land <=128, occupancy reaches 16 waves/CU anyway.
// K-order per acc element unchanged -> bit-identical output.
// ---------------------------------------------------------------------------
#define GLD16(gp, lp) \
    __builtin_amdgcn_global_load_lds( \
        (const __attribute__((address_space(1))) void*)(gp), \
        (__attribute__((address_space(3))) void*)(lp), 16, 0, 0)

__global__ __launch_bounds__(256, 3) void simmax_kernel(
    const unsigned short* __restrict__ Ahg, const unsigned short* __restrict__ Bhg,
    float* __restrict__ p1v, int* __restrict__ p1i,
    float* __restrict__ p2v, int* __restrict__ p2i)
{
    // A tile only: 128 rows x 64 shorts = 16 KB, single buffer
    __shared__ unsigned short lds[8192];

    const int tid    = threadIdx.x;          // 0..255
    const int L      = tid & 63;
    const int w      = tid >> 6;             // 0..3
    const int lane15 = L & 15;
    const int quad   = L >> 4;
    const int wr     = w >> 1;               // 0..1 (M half)
    const int wc     = w & 1;                // 0..1 (N half)
    const int row0   = blockIdx.x * 128;
    const int c0     = blockIdx.y * 128;

    // A staging: 4 issues, each covers 32 rows (256 thr x 16 B = 4 KB).
    // lane writes LDS linearly; global source pre-swizzled: granule
    // scol = (tid&7) ^ (row&7), row = tid>>3 (row&7 == (tid>>3)&7 since
    // issue offsets are multiples of 32 rows).
    const int scol = (tid & 7) ^ ((tid >> 3) & 7);
    const unsigned short* aB = Ahg + (size_t)(row0 + (tid >> 3)) * D_DIM + scol * 8;
    const int wofs = w * 512;                // shorts: (w*8 rows) * 64

#define STAGE_A(kb) do { \
    GLD16(aB + (kb),           &lds[0    + wofs]); \
    GLD16(aB + 32768  + (kb),  &lds[2048 + wofs]); \
    GLD16(aB + 65536  + (kb),  &lds[4096 + wofs]); \
    GLD16(aB + 98304  + (kb),  &lds[6144 + wofs]); \
} while (0)

    // B fragment bases: per rB-tile t, lane reads row c0 + wc*64 + t*16 +
    // lane15, k-shorts kb + h*32 + quad*8 (natural layout, no swizzle).
    const unsigned short* bF[4];
    #pragma unroll
    for (int t = 0; t < 4; ++t)
        bF[t] = Bhg + (size_t)(c0 + wc * 64 + t * 16 + lane15) * D_DIM + quad * 8;

    v4f acc[4][4];
    #pragma unroll
    for (int mt = 0; mt < 4; ++mt)
        #pragma unroll
        for (int nt = 0; nt < 4; ++nt) acc[mt][nt] = (v4f)0.0f;

    // A fragment geometry: rows * 64 shorts (128-B rows = full bank wrap)
    int rAo[4];
    #pragma unroll
    for (int t = 0; t < 4; ++t) rAo[t] = (wr * 64 + t * 16 + lane15) * 64;
    const int s7 = lane15 & 7;
    const int cq[2] = { (quad ^ s7) * 8, ((4 + quad) ^ s7) * 8 };  // shorts

    for (int kc = 0; kc < D_DIM / 64; ++kc) {
        const int kb = kc * 64;
        STAGE_A(kb);
        // B fragments for this K-tile, both halves, direct from global (L2).
        // Issued before the barrier: latency hides under the staging drain.
        v8s fb[2][4];
        #pragma unroll
        for (int h = 0; h < 2; ++h)
            #pragma unroll
            for (int t = 0; t < 4; ++t)
                fb[h][t] = *(const v8s*)(bF[t] + kb + h * 32);
        __syncthreads();                     // A resident, fb regs ready

        #pragma unroll
        for (int h = 0; h < 2; ++h) {
            v8s fah[4];
            #pragma unroll
            for (int t = 0; t < 4; ++t)
                fah[t] = *(const v8s*)&lds[rAo[t] + cq[h]];
            #pragma unroll
            for (int mt = 0; mt < 4; ++mt)
                #pragma unroll
                for (int nt = 0; nt < 4; ++nt)
                    acc[mt][nt] = __builtin_amdgcn_mfma_f32_16x16x32_bf16(
                        fah[mt], fb[h][nt], acc[mt][nt], 0, 0, 0);
        }
        __syncthreads();                     // A reads done before overwrite
    }

    // fused top-2 epilogue (R6-proven). C/D: col = lane&15, row = quad*4 + reg.
    const int pc = blockIdx.y * 2 + wc;      // 0..63 column chunk id (64 cols)
    #pragma unroll
    for (int mt = 0; mt < 4; ++mt) {
        #pragma unroll
        for (int r = 0; r < 4; ++r) {
            float a1v = acc[mt][0][r];
            int   a1i = c0 + wc * 64 + 0 * 16 + lane15;
            float a2v = -1e30f;
            int   a2i = 0x7fffffff;
            #pragma unroll
            for (int nt = 1; nt < 4; ++nt) {
                float v  = acc[mt][nt][r];
                int   ci = c0 + wc * 64 + nt * 16 + lane15;
                if (better_vi(v, ci, a1v, a1i))      { a2v = a1v; a2i = a1i; a1v = v; a1i = ci; }
                else if (better_vi(v, ci, a2v, a2i)) { a2v = v;   a2i = ci; }
            }
            #pragma unroll
            for (int off = 8; off; off >>= 1) {
                float b1v = __shfl_down(a1v, off, 64); int b1i = __shfl_down(a1i, off, 64);
                float b2v = __shfl_down(a2v, off, 64); int b2i = __shfl_down(a2i, off, 64);
                if (better_vi(b1v, b1i, a1v, a1i)) {
                    if (better_vi(a1v, a1i, b2v, b2i)) { a2v = a1v; a2i = a1i; }
                    else                               { a2v = b2v; a2i = b2i; }
                    a1v = b1v; a1i = b1i;
                } else if (better_vi(b1v, b1i, a2v, a2i)) {
                    a2v = b1v; a2i = b1i;
                }
            }
            if (lane15 == 0) {
                int rg = row0 + wr * 64 + mt * 16 + quad * 4 + r;
                size_t ix = (size_t)rg * 64 + pc;  // [row][chunk] layout
                p1v[ix] = a1v; p1i[ix] = a1i;
                p2v[ix] = a2v; p2i[ix] = a2i;
            }
        }
    }
}

// ---------------------------------------------------------------------------
// Kernel 3: R3/R5-proven finalize (wave per row, 4 rows/block, j-outer MLP
// rescore). Unchanged.
// ---------------------------------------------------------------------------
__global__ __launch_bounds__(256) void finalize_kernel(
    const float* __restrict__ emb, const float* __restrict__ cen,
    const float* __restrict__ inv_a, const float* __restrict__ inv_b,
    const float* __restrict__ p1v, const int* __restrict__ p1i,
    const float* __restrict__ p2v, const int* __restrict__ p2i,
    float* __restrict__ out)
{
    const int lane = threadIdx.x & 63;
    const int row  = blockIdx.x * 4 + (threadIdx.x >> 6);
    const size_t base = (size_t)row * 64 + lane;

    float v[4]; int ix[4];
    v[0] = p1v[base]; ix[0] = p1i[base];
    v[1] = p2v[base]; ix[1] = p2i[base];
    v[2] = -1e30f;    ix[2] = 0x7ffffffe;
    v[3] = -1e30f;    ix[3] = 0x7fffffff;

    #pragma unroll
    for (int off = 1; off < 64; off <<= 1) {
        float ov[4]; int oi[4];
        #pragma unroll
        for (int k = 0; k < 4; ++k) {
            ov[k] = __shfl_xor(v[k],  off, 64);
            oi[k] = __shfl_xor(ix[k], off, 64);
        }
        #pragma unroll
        for (int k = 0; k < 4; ++k) {
            float bv = ov[k]; int bi = oi[k];
            bool b0 = better_vi(bv, bi, v[0], ix[0]);
            bool b1 = better_vi(bv, bi, v[1], ix[1]);
            bool b2 = better_vi(bv, bi, v[2], ix[2]);
            bool b3 = better_vi(bv, bi, v[3], ix[3]);
            float nv3 = b2 ? v[2] : (b3 ? bv : v[3]); int ni3 = b2 ? ix[2] : (b3 ? bi : ix[3]);
            float nv2 = b1 ? v[1] : (b2 ? bv : v[2]); int ni2 = b1 ? ix[1] : (b2 ? bi : ix[2]);
            float nv1 = b0 ? v[0] : (b1 ? bv : v[1]); int ni1 = b0 ? ix[0] : (b1 ? bi : ix[1]);
            float nv0 = b0 ? bv   : v[0];             int ni0 = b0 ? bi    : ix[0];
            v[0] = nv0; ix[0] = ni0; v[1] = nv1; ix[1] = ni1;
            v[2] = nv2; ix[2] = ni2; v[3] = nv3; ix[3] = ni3;
        }
    }

    const float* er = emb + (size_t)row * D_DIM;
    const float* cr0 = cen + (size_t)ix[0] * D_DIM;
    const float* cr1 = cen + (size_t)ix[1] * D_DIM;
    const float* cr2 = cen + (size_t)ix[2] * D_DIM;
    const float* cr3 = cen + (size_t)ix[3] * D_DIM;

    float d[4] = { 0.0f, 0.0f, 0.0f, 0.0f };
    #pragma unroll
    for (int j = 0; j < 4; ++j) {
        int e = (j * 64 + lane) * 4;
        float4 ev = *(const float4*)(er  + e);
        float4 c0 = *(const float4*)(cr0 + e);
        float4 c1 = *(const float4*)(cr1 + e);
        float4 c2 = *(const float4*)(cr2 + e);
        float4 c3 = *(const float4*)(cr3 + e);
        d[0] += ev.x * c0.x + ev.y * c0.y + ev.z * c0.z + ev.w * c0.w;
        d[1] += ev.x * c1.x + ev.y * c1.y + ev.z * c1.z + ev.w * c1.w;
        d[2] += ev.x * c2.x + ev.y * c2.y + ev.z * c2.z + ev.w * c2.w;
        d[3] += ev.x * c3.x + ev.y * c3.y + ev.z * c3.z + ev.w * c3.w;
    }
    #pragma unroll
    for (int off = 1; off < 64; off <<= 1) {
        #pragma unroll
        for (int c = 0; c < 4; ++c) d[c] += __shfl_xor(d[c], off, 64);
    }

    if (lane == 0) {
        const float ia = inv_a[row];
        float m = -1e30f; int ci = 0x7fffffff;
        #pragma unroll
        for (int c = 0; c < 4; ++c) {
            float s = d[c] * ia * inv_b[ix[c]];
            if (better_vi(s, ix[c], m, ci)) { m = s; ci = ix[c]; }
        }
        if (m <= 0.0f) ci = 0;  // all sims clip to 0 -> argmax = 0
        float ms = fminf(fmaxf(m, 0.0f), 1.0f);
        out[row]          = fminf(fmaxf(sqrtf(1.0f - ms), 0.0f), 1.0f);
        out[B_ROWS + row] = (float)ci;
    }
}

// ---------------------------------------------------------------------------
// Workspace (~33 MB): Ah 16MB | Bh 8MB | inv_a 32KB | inv_b 16KB |
//                     p1v/p1i/p2v/p2i 2MB each ([row][chunk] layout)
// ---------------------------------------------------------------------------
extern "C" void kernel_launch(void* const* d_in, const int* in_sizes, int n_in,
                              void* d_out, int out_size, void* d_ws, size_t ws_size,
                              hipStream_t stream)
{
    const float* emb = (const float*)d_in[0];
    const float* cen = (const float*)d_in[1];
    float* out = (float*)d_out;

    unsigned short* Ahp = (unsigned short*)d_ws;
    unsigned short* Bhp = Ahp + (size_t)B_ROWS * D_DIM;
    float* inv_a = (float*)(Bhp + (size_t)C_COLS * D_DIM);
    float* inv_b = inv_a + B_ROWS;
    float* p1v   = inv_b + C_COLS;
    int*   p1i   = (int*)(p1v + (size_t)64 * B_ROWS);
    float* p2v   = (float*)(p1i + (size_t)64 * B_ROWS);
    int*   p2i   = (int*)(p2v + (size_t)64 * B_ROWS);

    prep_kernel<<<(B_ROWS + C_COLS) / 4, 256, 0, stream>>>(emb, cen, Ahp, Bhp, inv_a, inv_b);

    dim3 grid(B_ROWS / 128, C_COLS / 128);
    simmax_kernel<<<grid, 256, 0, stream>>>(Ahp, Bhp, p1v, p1i, p2v, p2i);

    finalize_kernel<<<B_ROWS / 4, 256, 0, stream>>>(emb, cen, inv_a, inv_b,
                                                    p1v, p1i, p2v, p2i, out);
}

// Round 9
// 211.897 us; speedup vs baseline: 1.2916x; 1.2916x over previous
//
#include <hip/hip_runtime.h>
#include <math.h>

#define B_ROWS 8192
#define C_COLS 4096
#define D_DIM  1024
#define EPSN   1e-12f

typedef float v4f __attribute__((ext_vector_type(4)));
typedef short v8s __attribute__((ext_vector_type(8)));

__device__ __forceinline__ unsigned short bf16_rtn(float x) {
    unsigned int u = __float_as_uint(x);
    u += 0x7fffu + ((u >> 16) & 1u);
    return (unsigned short)(u >> 16);
}

// strict total order (value desc, index asc) == first-occurrence argmax
__device__ __forceinline__ bool better_vi(float v, int i, float V, int I) {
    return (v > V) || (v == V && i < I);
}

// ---------------------------------------------------------------------------
// Kernel 1: wave-per-row normalize + bf16 convert. (R3-proven, unchanged)
// ---------------------------------------------------------------------------
__global__ __launch_bounds__(256) void prep_kernel(
    const float* __restrict__ emb, const float* __restrict__ cen,
    unsigned short* __restrict__ Ah, unsigned short* __restrict__ Bh,
    float* __restrict__ inv_a, float* __restrict__ inv_b)
{
    const int lane = threadIdx.x & 63;
    const int wid  = blockIdx.x * 4 + (threadIdx.x >> 6);
    const float* src; unsigned short* dst; float* invp; int r;
    if (wid < B_ROWS) { src = emb; r = wid;          dst = Ah; invp = inv_a; }
    else              { src = cen; r = wid - B_ROWS; dst = Bh; invp = inv_b; }

    const float* rp = src + (size_t)r * D_DIM;
    float4 v[4];
    float ss = 0.0f;
    #pragma unroll
    for (int j = 0; j < 4; ++j) {
        v[j] = *(const float4*)(rp + (j * 64 + lane) * 4);
        ss += v[j].x * v[j].x + v[j].y * v[j].y + v[j].z * v[j].z + v[j].w * v[j].w;
    }
    #pragma unroll
    for (int off = 1; off < 64; off <<= 1) ss += __shfl_xor(ss, off, 64);

    const float iv = 1.0f / fmaxf(sqrtf(ss), EPSN);
    if (lane == 0) invp[r] = iv;

    unsigned short* dp = dst + (size_t)r * D_DIM;
    #pragma unroll
    for (int j = 0; j < 4; ++j) {
        ushort4 H;
        H.x = bf16_rtn(v[j].x * iv);
        H.y = bf16_rtn(v[j].y * iv);
        H.z = bf16_rtn(v[j].z * iv);
        H.w = bf16_rtn(v[j].w * iv);
        *(ushort4*)(dp + (j * 64 + lane) * 4) = H;
    }
}

// ---------------------------------------------------------------------------
// Kernel 2 (R14): R10 geometry + counted-vmcnt triple-buffer pipeline.
//   256x128 tile, 512 thr (4Mx2N waves), acc[4][4] -- unchanged from R10
//   (the only variant family that held 2 blocks/CU = 16 waves).
//   NEW: BK=32 K-steps (32 iters), 3 buffers x 24 KB = 72 KB (2 blk/CU
//   still fits: 144 <= 160 KB). Stage tile t+2 during tile t. ONE raw
//   s_barrier per K-step, preceded by s_waitcnt vmcnt(3): waits only THIS
//   wave's tile-t loads (t+1/t+2's 3+3 stay in flight); barrier then makes
//   all waves' tile-t staging resident. vmcnt never drains to 0 until t=31.
//   FIFO per wave: prologue {t0x3,t1x3}; iter t: vmcnt(3) retires tile-t,
//   stage(t+2) pushes 3 -> invariant holds; t=31 uses vmcnt(0).
//   64-B-row LDS layout, granule swizzle g^(row&3): bank-group =
//   16*(r&1) + 4*(quad^(r&3)) -> 8 lanes per 4-bank group, balanced =
//   conflict-free. Same ascending K-chunk order as R10 -> bit-identical.
// ---------------------------------------------------------------------------
#define GLD16(gp, lp) \
    __builtin_amdgcn_global_load_lds( \
        (const __attribute__((address_space(1))) void*)(gp), \
        (__attribute__((address_space(3))) void*)(lp), 16, 0, 0)

__global__ __launch_bounds__(512, 4) void simmax_kernel(
    const unsigned short* __restrict__ Ahg, const unsigned short* __restrict__ Bhg,
    float* __restrict__ p1v, int* __restrict__ p1i,
    float* __restrict__ p2v, int* __restrict__ p2i)
{
    // buffer = A(256x32) 8192 + B(128x32) 4096 = 12288 shorts (24 KB); x3
    __shared__ unsigned short lds[3 * 12288];

    const int tid    = threadIdx.x;          // 0..511
    const int L      = tid & 63;
    const int w      = tid >> 6;             // 0..7
    const int lane15 = L & 15;
    const int quad   = L >> 4;
    const int wr     = w >> 1;               // 0..3 (M quarter)
    const int wc     = w & 1;                // 0..1 (N half)
    const int row0   = blockIdx.x * 256;
    const int c0     = blockIdx.y * 128;

    // staging: per issue a wave fills 16 rows x 32 shorts (1 KB). Lane L:
    // row = tid>>2 (block-wide), phys granule L&3 <- logical sg (pre-swizzled
    // source so LDS dest stays linear).
    const int sg = (tid & 3) ^ ((tid >> 2) & 3);
    const unsigned short* aS = Ahg + (size_t)(row0 + (tid >> 2)) * D_DIM + sg * 8;
    const unsigned short* bS = Bhg + (size_t)(c0   + (tid >> 2)) * D_DIM + sg * 8;
    const int wS = w * 512;                  // shorts: (w*16 rows) * 32

    // 3 issues/thread/K-step: A rows {0,128}, B rows {0}
#define STAGE(bo, kb) do { \
    GLD16(aS + (kb),          &lds[(bo) + 0    + wS]); \
    GLD16(aS + 131072 + (kb), &lds[(bo) + 4096 + wS]); \
    GLD16(bS + (kb),          &lds[(bo) + 8192 + wS]); \
} while (0)

    v4f acc[4][4];
    #pragma unroll
    for (int mt = 0; mt < 4; ++mt)
        #pragma unroll
        for (int nt = 0; nt < 4; ++nt) acc[mt][nt] = (v4f)0.0f;

    // fragment geometry: rows * 32 shorts (64-B rows); granule swz g^(r&3)
    int rAo[4], rBo[4];
    #pragma unroll
    for (int t = 0; t < 4; ++t) {
        rAo[t] = (wr * 64 + t * 16 + lane15) * 32;
        rBo[t] = 8192 + (wc * 64 + t * 16 + lane15) * 32;
    }
    const int cq = (quad ^ (lane15 & 3)) * 8;   // shorts

    // prologue: stage tiles 0 and 1 (6 loads in flight)
    STAGE(0, 0);
    STAGE(12288, 32);

    int b0 = 0, b1 = 12288, b2 = 24576;      // cur, next, stage-target
    for (int t = 0; t < 32; ++t) {
        // counted wait: retire tile t's 3 loads; t+1/t+2's stay in flight
        if (t == 31) asm volatile("s_waitcnt vmcnt(0)" ::: "memory");
        else         asm volatile("s_waitcnt vmcnt(3)" ::: "memory");
        __builtin_amdgcn_s_barrier();        // all waves' tile-t staging done;
                                             // all waves' tile-(t-1) reads done
        __builtin_amdgcn_sched_barrier(0);
        if (t < 30) STAGE(b2, (t + 2) * 32); // into buffer freed at this barrier

        v8s fa[4], fb[4];
        #pragma unroll
        for (int q = 0; q < 4; ++q) {
            fa[q] = *(const v8s*)&lds[b0 + rAo[q] + cq];
            fb[q] = *(const v8s*)&lds[b0 + rBo[q] + cq];
        }
        #pragma unroll
        for (int mt = 0; mt < 4; ++mt)
            #pragma unroll
            for (int nt = 0; nt < 4; ++nt)
                acc[mt][nt] = __builtin_amdgcn_mfma_f32_16x16x32_bf16(
                    fa[mt], fb[nt], acc[mt][nt], 0, 0, 0);

        const int tb = b0; b0 = b1; b1 = b2; b2 = tb;
    }

    // fused top-2 epilogue (R6/R10-proven). C/D: col=lane&15, row=quad*4+reg.
    const int pc = blockIdx.y * 2 + wc;      // 0..63 column chunk id
    #pragma unroll
    for (int mt = 0; mt < 4; ++mt) {
        #pragma unroll
        for (int r = 0; r < 4; ++r) {
            float a1v = acc[mt][0][r];
            int   a1i = c0 + wc * 64 + 0 * 16 + lane15;
            float a2v = -1e30f;
            int   a2i = 0x7fffffff;
            #pragma unroll
            for (int nt = 1; nt < 4; ++nt) {
                float v  = acc[mt][nt][r];
                int   ci = c0 + wc * 64 + nt * 16 + lane15;
                if (better_vi(v, ci, a1v, a1i))      { a2v = a1v; a2i = a1i; a1v = v; a1i = ci; }
                else if (better_vi(v, ci, a2v, a2i)) { a2v = v;   a2i = ci; }
            }
            #pragma unroll
            for (int off = 8; off; off >>= 1) {
                float b1v = __shfl_down(a1v, off, 64); int b1i = __shfl_down(a1i, off, 64);
                float b2v = __shfl_down(a2v, off, 64); int b2i = __shfl_down(a2i, off, 64);
                if (better_vi(b1v, b1i, a1v, a1i)) {
                    if (better_vi(a1v, a1i, b2v, b2i)) { a2v = a1v; a2i = a1i; }
                    else                               { a2v = b2v; a2i = b2i; }
                    a1v = b1v; a1i = b1i;
                } else if (better_vi(b1v, b1i, a2v, a2i)) {
                    a2v = b1v; a2i = b1i;
                }
            }
            if (lane15 == 0) {
                int rg = row0 + wr * 64 + mt * 16 + quad * 4 + r;
                size_t ix = (size_t)rg * 64 + pc;  // [row][chunk] layout
                p1v[ix] = a1v; p1i[ix] = a1i;
                p2v[ix] = a2v; p2i[ix] = a2i;
            }
        }
    }
}

// ---------------------------------------------------------------------------
// Kernel 3: R3/R5-proven finalize (wave per row, 4 rows/block, j-outer MLP
// rescore). Unchanged.
// ---------------------------------------------------------------------------
__global__ __launch_bounds__(256) void finalize_kernel(
    const float* __restrict__ emb, const float* __restrict__ cen,
    const float* __restrict__ inv_a, const float* __restrict__ inv_b,
    const float* __restrict__ p1v, const int* __restrict__ p1i,
    const float* __restrict__ p2v, const int* __restrict__ p2i,
    float* __restrict__ out)
{
    const int lane = threadIdx.x & 63;
    const int row  = blockIdx.x * 4 + (threadIdx.x >> 6);
    const size_t base = (size_t)row * 64 + lane;

    float v[4]; int ix[4];
    v[0] = p1v[base]; ix[0] = p1i[base];
    v[1] = p2v[base]; ix[1] = p2i[base];
    v[2] = -1e30f;    ix[2] = 0x7ffffffe;
    v[3] = -1e30f;    ix[3] = 0x7fffffff;

    #pragma unroll
    for (int off = 1; off < 64; off <<= 1) {
        float ov[4]; int oi[4];
        #pragma unroll
        for (int k = 0; k < 4; ++k) {
            ov[k] = __shfl_xor(v[k],  off, 64);
            oi[k] = __shfl_xor(ix[k], off, 64);
        }
        #pragma unroll
        for (int k = 0; k < 4; ++k) {
            float bv = ov[k]; int bi = oi[k];
            bool b0 = better_vi(bv, bi, v[0], ix[0]);
            bool b1 = better_vi(bv, bi, v[1], ix[1]);
            bool b2 = better_vi(bv, bi, v[2], ix[2]);
            bool b3 = better_vi(bv, bi, v[3], ix[3]);
            float nv3 = b2 ? v[2] : (b3 ? bv : v[3]); int ni3 = b2 ? ix[2] : (b3 ? bi : ix[3]);
            float nv2 = b1 ? v[1] : (b2 ? bv : v[2]); int ni2 = b1 ? ix[1] : (b2 ? bi : ix[2]);
            float nv1 = b0 ? v[0] : (b1 ? bv : v[1]); int ni1 = b0 ? ix[0] : (b1 ? bi : ix[1]);
            float nv0 = b0 ? bv   : v[0];             int ni0 = b0 ? bi    : ix[0];
            v[0] = nv0; ix[0] = ni0; v[1] = nv1; ix[1] = ni1;
            v[2] = nv2; ix[2] = ni2; v[3] = nv3; ix[3] = ni3;
        }
    }

    const float* er = emb + (size_t)row * D_DIM;
    const float* cr0 = cen + (size_t)ix[0] * D_DIM;
    const float* cr1 = cen + (size_t)ix[1] * D_DIM;
    const float* cr2 = cen + (size_t)ix[2] * D_DIM;
    const float* cr3 = cen + (size_t)ix[3] * D_DIM;

    float d[4] = { 0.0f, 0.0f, 0.0f, 0.0f };
    #pragma unroll
    for (int j = 0; j < 4; ++j) {
        int e = (j * 64 + lane) * 4;
        float4 ev = *(const float4*)(er  + e);
        float4 c0 = *(const float4*)(cr0 + e);
        float4 c1 = *(const float4*)(cr1 + e);
        float4 c2 = *(const float4*)(cr2 + e);
        float4 c3 = *(const float4*)(cr3 + e);
        d[0] += ev.x * c0.x + ev.y * c0.y + ev.z * c0.z + ev.w * c0.w;
        d[1] += ev.x * c1.x + ev.y * c1.y + ev.z * c1.z + ev.w * c1.w;
        d[2] += ev.x * c2.x + ev.y * c2.y + ev.z * c2.z + ev.w * c2.w;
        d[3] += ev.x * c3.x + ev.y * c3.y + ev.z * c3.z + ev.w * c3.w;
    }
    #pragma unroll
    for (int off = 1; off < 64; off <<= 1) {
        #pragma unroll
        for (int c = 0; c < 4; ++c) d[c] += __shfl_xor(d[c], off, 64);
    }

    if (lane == 0) {
        const float ia = inv_a[row];
        float m = -1e30f; int ci = 0x7fffffff;
        #pragma unroll
        for (int c = 0; c < 4; ++c) {
            float s = d[c] * ia * inv_b[ix[c]];
            if (better_vi(s, ix[c], m, ci)) { m = s; ci = ix[c]; }
        }
        if (m <= 0.0f) ci = 0;  // all sims clip to 0 -> argmax = 0
        float ms = fminf(fmaxf(m, 0.0f), 1.0f);
        out[row]          = fminf(fmaxf(sqrtf(1.0f - ms), 0.0f), 1.0f);
        out[B_ROWS + row] = (float)ci;
    }
}

// ---------------------------------------------------------------------------
// Workspace (~33 MB): Ah 16MB | Bh 8MB | inv_a 32KB | inv_b 16KB |
//                     p1v/p1i/p2v/p2i 2MB each ([row][chunk] layout)
// ---------------------------------------------------------------------------
extern "C" void kernel_launch(void* const* d_in, const int* in_sizes, int n_in,
                              void* d_out, int out_size, void* d_ws, size_t ws_size,
                              hipStream_t stream)
{
    const float* emb = (const float*)d_in[0];
    const float* cen = (const float*)d_in[1];
    float* out = (float*)d_out;

    unsigned short* Ahp = (unsigned short*)d_ws;
    unsigned short* Bhp = Ahp + (size_t)B_ROWS * D_DIM;
    float* inv_a = (float*)(Bhp + (size_t)C_COLS * D_DIM);
    float* inv_b = inv_a + B_ROWS;
    float* p1v   = inv_b + C_COLS;
    int*   p1i   = (int*)(p1v + (size_t)64 * B_ROWS);
    float* p2v   = (float*)(p1i + (size_t)64 * B_ROWS);
    int*   p2i   = (int*)(p2v + (size_t)64 * B_ROWS);

    prep_kernel<<<(B_ROWS + C_COLS) / 4, 256, 0, stream>>>(emb, cen, Ahp, Bhp, inv_a, inv_b);

    dim3 grid(B_ROWS / 256, C_COLS / 128);
    simmax_kernel<<<grid, 512, 0, stream>>>(Ahp, Bhp, p1v, p1i, p2v, p2i);

    finalize_kernel<<<B_ROWS / 4, 256, 0, stream>>>(emb, cen, inv_a, inv_b,
                                                    p1v, p1i, p2v, p2i, out);
}